// Round 3
// baseline (1097.679 us; speedup 1.0000x reference)
//
#include <hip/hip_runtime.h>

#define N_VOXELS 150000
#define NP 60000
#define NK 27
#define CIN 32
#define COUT 64
#define BN_EPS 1e-5f
#define NELEM (N_VOXELS * COUT)

#define RVOX 128                                 // voxels per range (block)
#define RSHIFT 7
#define NR ((N_VOXELS + RVOX - 1) / RVOX)        // 1172 ranges
#define CAP 2048                                 // bucket cap (avg 1382, +18 sigma)

// ws layout (int32 units):
//   [0 .. NR)            range counters
//   [4096 .. 4224)       BN stats (float): sum[64], sumsq[64]
//   [8192 .. )           bucket lists, NR*CAP ints (~9.6 MB)
#define WS_CNT   0
#define WS_STATS 4096
#define WS_LIST  8192

// ---------------------------------------------------------------------------
// Kernel 1: build range buckets over the flat (k,p) rulebook.
// entry = (k<<25) | (vin<<7) | (vout & 127)  -- conv never reads in_idx again.
// ---------------------------------------------------------------------------
__global__ __launch_bounds__(256) void build_buckets(
    const int* __restrict__ in_idx,
    const int* __restrict__ out_idx,
    int* __restrict__ ws)
{
    const int idx = blockIdx.x * 256 + threadIdx.x;
    if (idx >= NK * NP) return;
    const int k    = idx / NP;
    const int vout = out_idx[idx];
    const int vin  = in_idx[idx];
    const int r    = vout >> RSHIFT;
    const int slot = atomicAdd(&ws[WS_CNT + r], 1);
    if (slot < CAP)
        ws[WS_LIST + r * CAP + slot] = (k << 25) | (vin << RSHIFT) | (vout & (RVOX - 1));
}

// ---------------------------------------------------------------------------
// Kernel 2: gather conv per range. k-bin entries in LDS, then per-k weight
// column in VGPRs (lane = cout); 2-entry software pipeline so feature loads
// of entry i+1 / kbin reads of i+2 overlap the FMAs of entry i.
// Epilogue: y = relu(acc+bias) coalesced store + fused BN stats.
// ---------------------------------------------------------------------------
__global__ __launch_bounds__(256, 3) void conv_gather(
    const float* __restrict__ features,
    const float* __restrict__ weight,
    const float* __restrict__ bias,
    const int* __restrict__ ws_i,
    float* __restrict__ out,
    float* __restrict__ stats)
{
    __shared__ float accum[RVOX * COUT];   // 32 KB
    __shared__ int   kbin[CAP];            // 8 KB
    __shared__ int   khist[NK];
    __shared__ int   koff[NK + 1];
    __shared__ int   kcur[NK];
    __shared__ float lsum[COUT];
    __shared__ float lsq[COUT];

    const int r    = blockIdx.x;
    const int tid  = threadIdx.x;
    const int lane = tid & 63;
    const int wid  = tid >> 6;

    int n = ws_i[WS_CNT + r];
    if (n > CAP) n = CAP;
    const int* list = ws_i + WS_LIST + (size_t)r * CAP;

    float4* acc4 = reinterpret_cast<float4*>(accum);
    for (int i = tid; i < RVOX * COUT / 4; i += 256) acc4[i] = float4{0.f, 0.f, 0.f, 0.f};
    if (tid < NK) khist[tid] = 0;
    if (tid < COUT) { lsum[tid] = 0.f; lsq[tid] = 0.f; }
    __syncthreads();

    for (int i = tid; i < n; i += 256) atomicAdd(&khist[list[i] >> 25], 1);
    __syncthreads();
    if (tid == 0) {
        int a = 0;
        for (int k = 0; k < NK; ++k) { koff[k] = a; kcur[k] = a; a += khist[k]; }
        koff[NK] = a;
    }
    __syncthreads();
    for (int i = tid; i < n; i += 256) {
        const int pk = list[i];
        kbin[atomicAdd(&kcur[pk >> 25], 1)] = pk;
    }
    __syncthreads();

    for (int k = 0; k < NK; ++k) {
        const int b0 = koff[k], b1 = koff[k + 1];
        if (b0 == b1) continue;
        float w[CIN];
        const float* wk = weight + k * (CIN * COUT) + lane;
#pragma unroll
        for (int c = 0; c < CIN; ++c) w[c] = wk[c * COUT];

        const int len   = b1 - b0;
        const int chunk = (len + 3) >> 2;
        const int s     = b0 + wid * chunk;
        const int e     = (s + chunk < b1) ? (s + chunk) : b1;
        if (s >= e) continue;

        int pkA = kbin[s];
        int pkB = (s + 1 < e) ? kbin[s + 1] : -1;
        for (int i = s; i < e; i += 2) {
            const int nA = (i + 2 < e) ? kbin[i + 2] : 0;    // prefetch next pair
            const int nB = (i + 3 < e) ? kbin[i + 3] : -1;

            const bool hasB = (pkB >= 0);
            const int  pb   = hasB ? pkB : pkA;
            const int vinA = (pkA >> RSHIFT) & 0x3FFFF, lvA = pkA & (RVOX - 1);
            const int vinB = (pb  >> RSHIFT) & 0x3FFFF, lvB = pb  & (RVOX - 1);
            const float4* fA = reinterpret_cast<const float4*>(features + (size_t)vinA * CIN);
            const float4* fB = reinterpret_cast<const float4*>(features + (size_t)vinB * CIN);

            float4 a0[8], a1[8];
#pragma unroll
            for (int q = 0; q < 8; ++q) a0[q] = fA[q];
#pragma unroll
            for (int q = 0; q < 8; ++q) a1[q] = fB[q];

            float s0 = 0.f, s1 = 0.f, s2 = 0.f, s3 = 0.f;
#pragma unroll
            for (int q = 0; q < 8; ++q) {
                s0 = fmaf(a0[q].x, w[4 * q + 0], s0);
                s1 = fmaf(a0[q].y, w[4 * q + 1], s1);
                s2 = fmaf(a0[q].z, w[4 * q + 2], s2);
                s3 = fmaf(a0[q].w, w[4 * q + 3], s3);
            }
            atomicAdd(&accum[lvA * COUT + lane], (s0 + s1) + (s2 + s3));

            float t0 = 0.f, t1 = 0.f, t2 = 0.f, t3 = 0.f;
#pragma unroll
            for (int q = 0; q < 8; ++q) {
                t0 = fmaf(a1[q].x, w[4 * q + 0], t0);
                t1 = fmaf(a1[q].y, w[4 * q + 1], t1);
                t2 = fmaf(a1[q].z, w[4 * q + 2], t2);
                t3 = fmaf(a1[q].w, w[4 * q + 3], t3);
            }
            if (hasB) atomicAdd(&accum[lvB * COUT + lane], (t0 + t1) + (t2 + t3));

            pkA = nA;
            pkB = nB;
        }
    }
    __syncthreads();

    // epilogue: y = relu(acc + bias), coalesced store, fused BN stats
    const int v0 = r * RVOX;
    const int nv = (N_VOXELS - v0 < RVOX) ? (N_VOXELS - v0) : RVOX;
    const float b = bias[lane];                 // channel == tid&63 (stride 256)
    float rs = 0.f, rq = 0.f;
    for (int i = tid; i < nv * COUT; i += 256) {
        float y = accum[i] + b;
        y = fmaxf(y, 0.f);
        out[(size_t)v0 * COUT + i] = y;
        rs += y;
        rq += y * y;
    }
    atomicAdd(&lsum[lane], rs);
    atomicAdd(&lsq[lane], rq);
    __syncthreads();
    if (tid < COUT) atomicAdd(&stats[tid], lsum[tid]);
    else if (tid < 2 * COUT) atomicAdd(&stats[tid], lsq[tid - COUT]);
}

// ---------------------------------------------------------------------------
// Kernel 3: in-place BN apply on y (already ReLU'd), float4-vectorized.
// ---------------------------------------------------------------------------
__global__ __launch_bounds__(256) void bn_apply(
    float* __restrict__ buf,
    const float* __restrict__ stats,
    const float* __restrict__ gamma,
    const float* __restrict__ beta)
{
    const float inv_n = 1.f / (float)N_VOXELS;
    const int cg = (threadIdx.x & 15) * 4;
    float sc[4], sh[4];
#pragma unroll
    for (int j = 0; j < 4; ++j) {
        const int c = cg + j;
        const float mean = stats[c] * inv_n;
        const float var  = stats[COUT + c] * inv_n - mean * mean;
        sc[j] = gamma[c] * rsqrtf(var + BN_EPS);
        sh[j] = beta[c] - mean * sc[j];
    }
    const int tid    = blockIdx.x * 256 + threadIdx.x;
    const int stride = gridDim.x * 256;
    float4* buf4 = reinterpret_cast<float4*>(buf);
    for (int i = tid; i < NELEM / 4; i += stride) {
        float4 y = buf4[i];
        y.x = fmaf(y.x, sc[0], sh[0]);
        y.y = fmaf(y.y, sc[1], sh[1]);
        y.z = fmaf(y.z, sc[2], sh[2]);
        y.w = fmaf(y.w, sc[3], sh[3]);
        buf4[i] = y;
    }
}

extern "C" void kernel_launch(void* const* d_in, const int* in_sizes, int n_in,
                              void* d_out, int out_size, void* d_ws, size_t ws_size,
                              hipStream_t stream) {
    const float* features = (const float*)d_in[0];
    const int*   in_idx   = (const int*)d_in[1];
    const int*   out_idx  = (const int*)d_in[2];
    const float* weight   = (const float*)d_in[3];
    const float* bias     = (const float*)d_in[4];
    const float* gamma    = (const float*)d_in[5];
    const float* beta     = (const float*)d_in[6];
    float* out   = (float*)d_out;
    int*   ws    = (int*)d_ws;
    float* stats = (float*)d_ws + WS_STATS;

    // zero counters + stats (first 32 KB); bucket payload needs no init
    hipMemsetAsync(d_ws, 0, (size_t)WS_LIST * sizeof(int), stream);

    build_buckets<<<(NK * NP + 255) / 256, 256, 0, stream>>>(in_idx, out_idx, ws);

    conv_gather<<<NR, 256, 0, stream>>>(features, weight, bias, ws, out, stats);

    bn_apply<<<2048, 256, 0, stream>>>(out, stats, gamma, beta);
}

// Round 5
// 990.061 us; speedup vs baseline: 1.1087x; 1.1087x over previous
//
#include <hip/hip_runtime.h>

// Round 4 = re-bench of round-3 proposal (prior attempt hit GPUAcquisitionTimeout,
// never measured). Theory under test: block-wide LDS staging of 64 feature rows
// per tile removes the dependent-load latency wall (r2/r3: VALUBusy 17%, HBM 3%).

#define N_VOXELS 150000
#define NP 60000
#define NK 27
#define CIN 32
#define COUT 64
#define BN_EPS 1e-5f
#define NELEM (N_VOXELS * COUT)

#define RVOX 64                                  // voxels per range (block)
#define RSHIFT 6
#define NR ((N_VOXELS + RVOX - 1) / RVOX)        // 2344 ranges
#define CAP 1024                                 // bucket cap (avg 691, +12 sigma)

// ws layout (int32 units):
//   [0 .. NR)        range counters
//   [4096 .. 4224)   BN stats (float): sum[64], sumsq[64]
//   [8192 .. )       bucket lists, NR*CAP ints (~9.6 MB)
#define WS_CNT   0
#define WS_STATS 4096
#define WS_LIST  8192

// ---------------------------------------------------------------------------
// Kernel 1: build range buckets over the flat (k,p) rulebook.
// entry = (k<<24) | (vin<<6) | (vout & 63); vin < 2^18 fits bits 6..23.
// ---------------------------------------------------------------------------
__global__ __launch_bounds__(256) void build_buckets(
    const int* __restrict__ in_idx,
    const int* __restrict__ out_idx,
    int* __restrict__ ws)
{
    const int idx = blockIdx.x * 256 + threadIdx.x;
    if (idx >= NK * NP) return;
    const int k    = idx / NP;
    const int vout = out_idx[idx];
    const int vin  = in_idx[idx];
    const int r    = vout >> RSHIFT;
    const int slot = atomicAdd(&ws[WS_CNT + r], 1);
    if (slot < CAP)
        ws[WS_LIST + r * CAP + slot] = (k << 24) | (vin << RSHIFT) | (vout & (RVOX - 1));
}

// ---------------------------------------------------------------------------
// Kernel 2: gather conv per range, k-binned, with block-wide LDS staging.
// Per 64-entry tile: 256 threads stage 64 DIFFERENT feature rows (thread t ->
// row t/4, two float4 each) => 64 rows of MLP per tile instead of 1.
// Then each wave computes every-4th entry: 8 uniform ds_read_b128 (broadcast)
// + 32 FMA vs weight column in VGPRs (lane = cout) + ds_add into accum.
// Epilogue: y = relu(acc+bias) coalesced store + fused BN stats.
// ---------------------------------------------------------------------------
__global__ __launch_bounds__(256, 4) void conv_gather(
    const float* __restrict__ features,
    const float* __restrict__ weight,
    const float* __restrict__ bias,
    const int* __restrict__ ws_i,
    float* __restrict__ out,
    float* __restrict__ stats)
{
    __shared__ float  accum[RVOX * COUT];    // 16 KB
    __shared__ int    kbin[CAP];             // 4 KB
    __shared__ float4 fstage4[64 * 9];       // 9.2 KB, row stride 9 float4 (36 f)
    __shared__ int    khist[NK];
    __shared__ int    koff[NK + 1];
    __shared__ int    kcur[NK];
    __shared__ float  lsum[COUT];
    __shared__ float  lsq[COUT];

    const int r    = blockIdx.x;
    const int tid  = threadIdx.x;
    const int lane = tid & 63;
    const int wid  = tid >> 6;

    int n = ws_i[WS_CNT + r];
    if (n > CAP) n = CAP;
    const int* list = ws_i + WS_LIST + (size_t)r * CAP;

    float4* acc4 = reinterpret_cast<float4*>(accum);
    for (int i = tid; i < RVOX * COUT / 4; i += 256) acc4[i] = float4{0.f, 0.f, 0.f, 0.f};
    if (tid < NK) khist[tid] = 0;
    if (tid < COUT) { lsum[tid] = 0.f; lsq[tid] = 0.f; }
    __syncthreads();

    // histogram by k, then place into k-sorted bins
    for (int i = tid; i < n; i += 256) atomicAdd(&khist[list[i] >> 24], 1);
    __syncthreads();
    if (tid == 0) {
        int a = 0;
        for (int k = 0; k < NK; ++k) { koff[k] = a; kcur[k] = a; a += khist[k]; }
        koff[NK] = a;
    }
    __syncthreads();
    for (int i = tid; i < n; i += 256) {
        const int pk = list[i];
        kbin[atomicAdd(&kcur[pk >> 24], 1)] = pk;
    }
    __syncthreads();

    const int jrow = tid >> 2;          // staging row this thread fills (0..63)
    const int q0   = tid & 3;           // quad pair: q0 and q0+4

    for (int k = 0; k < NK; ++k) {
        const int b0 = koff[k], b1 = koff[k + 1];
        if (b0 == b1) continue;

        // weight column for this lane's cout, resident in VGPRs
        float w[CIN];
        const float* wk = weight + k * (CIN * COUT) + lane;
#pragma unroll
        for (int c = 0; c < CIN; ++c) w[c] = wk[c * COUT];

        for (int s = b0; s < b1; s += 64) {
            const int cnt = (b1 - s < 64) ? (b1 - s) : 64;

            // ---- gather: stage cnt feature rows, 64 rows in flight ----
            if (jrow < cnt) {
                const int pk  = kbin[s + jrow];
                const int vin = (pk >> RSHIFT) & 0x3FFFF;
                const float4* f4 = reinterpret_cast<const float4*>(features + (size_t)vin * CIN);
                float4 a = f4[q0];
                float4 b = f4[q0 + 4];
                fstage4[jrow * 9 + q0]     = a;
                fstage4[jrow * 9 + q0 + 4] = b;
            }
            __syncthreads();

            // ---- compute: each wave takes every-4th staged entry ----
            for (int j = wid; j < cnt; j += 4) {
                const int pk = kbin[s + j];              // uniform broadcast
                const int lv = pk & (RVOX - 1);
                float4 a[8];
#pragma unroll
                for (int q = 0; q < 8; ++q) a[q] = fstage4[j * 9 + q];   // uniform b128
                float s0 = 0.f, s1 = 0.f, s2 = 0.f, s3 = 0.f;
#pragma unroll
                for (int q = 0; q < 8; ++q) {
                    s0 = fmaf(a[q].x, w[4 * q + 0], s0);
                    s1 = fmaf(a[q].y, w[4 * q + 1], s1);
                    s2 = fmaf(a[q].z, w[4 * q + 2], s2);
                    s3 = fmaf(a[q].w, w[4 * q + 3], s3);
                }
                atomicAdd(&accum[lv * COUT + lane], (s0 + s1) + (s2 + s3));  // ds_add
            }
            __syncthreads();   // protect fstage before next tile overwrites
        }
    }
    __syncthreads();

    // epilogue: y = relu(acc + bias), coalesced store, fused BN stats
    const int v0 = r * RVOX;
    const int nv = (N_VOXELS - v0 < RVOX) ? (N_VOXELS - v0) : RVOX;
    const float b = bias[lane];            // channel == tid&63 (stride 256)
    float rs = 0.f, rq = 0.f;
    for (int i = tid; i < nv * COUT; i += 256) {
        float y = accum[i] + b;
        y = fmaxf(y, 0.f);
        out[(size_t)v0 * COUT + i] = y;
        rs += y;
        rq += y * y;
    }
    atomicAdd(&lsum[lane], rs);
    atomicAdd(&lsq[lane], rq);
    __syncthreads();
    if (tid < COUT) atomicAdd(&stats[tid], lsum[tid]);
    else if (tid < 2 * COUT) atomicAdd(&stats[tid], lsq[tid - COUT]);
}

// ---------------------------------------------------------------------------
// Kernel 3: in-place BN apply on y (already ReLU'd), float4-vectorized.
// ---------------------------------------------------------------------------
__global__ __launch_bounds__(256) void bn_apply(
    float* __restrict__ buf,
    const float* __restrict__ stats,
    const float* __restrict__ gamma,
    const float* __restrict__ beta)
{
    const float inv_n = 1.f / (float)N_VOXELS;
    const int cg = (threadIdx.x & 15) * 4;
    float sc[4], sh[4];
#pragma unroll
    for (int j = 0; j < 4; ++j) {
        const int c = cg + j;
        const float mean = stats[c] * inv_n;
        const float var  = stats[COUT + c] * inv_n - mean * mean;
        sc[j] = gamma[c] * rsqrtf(var + BN_EPS);
        sh[j] = beta[c] - mean * sc[j];
    }
    const int tid    = blockIdx.x * 256 + threadIdx.x;
    const int stride = gridDim.x * 256;
    float4* buf4 = reinterpret_cast<float4*>(buf);
    for (int i = tid; i < NELEM / 4; i += stride) {
        float4 y = buf4[i];
        y.x = fmaf(y.x, sc[0], sh[0]);
        y.y = fmaf(y.y, sc[1], sh[1]);
        y.z = fmaf(y.z, sc[2], sh[2]);
        y.w = fmaf(y.w, sc[3], sh[3]);
        buf4[i] = y;
    }
}

extern "C" void kernel_launch(void* const* d_in, const int* in_sizes, int n_in,
                              void* d_out, int out_size, void* d_ws, size_t ws_size,
                              hipStream_t stream) {
    const float* features = (const float*)d_in[0];
    const int*   in_idx   = (const int*)d_in[1];
    const int*   out_idx  = (const int*)d_in[2];
    const float* weight   = (const float*)d_in[3];
    const float* bias     = (const float*)d_in[4];
    const float* gamma    = (const float*)d_in[5];
    const float* beta     = (const float*)d_in[6];
    float* out   = (float*)d_out;
    int*   ws    = (int*)d_ws;
    float* stats = (float*)d_ws + WS_STATS;

    // zero counters + stats (first 32 KB); bucket payload needs no init
    hipMemsetAsync(d_ws, 0, (size_t)WS_LIST * sizeof(int), stream);

    build_buckets<<<(NK * NP + 255) / 256, 256, 0, stream>>>(in_idx, out_idx, ws);

    conv_gather<<<NR, 256, 0, stream>>>(features, weight, bias, ws, out, stats);

    bn_apply<<<2048, 256, 0, stream>>>(out, stats, gamma, beta);
}

// Round 7
// 882.779 us; speedup vs baseline: 1.2434x; 1.1215x over previous
//
#include <hip/hip_runtime.h>

// Round 7 = re-bench of round-5 proposal (round-6 attempt hit GPUAcquisitionTimeout,
// never measured). Theory under test: all four prior variants (630-770us) share
// per-entry wave-uniform 128B row broadcasts (global or LDS); if uniform reads
// replay per-lane instead of broadcasting, that pipe is the ~744us wall.
// Fix: fetch rows via s_load_dwordx16 (scalar cache, SGPRs), FMA with SGPR src.

#define N_VOXELS 150000
#define NP 60000
#define NK 27
#define CIN 32
#define COUT 64
#define BN_EPS 1e-5f
#define NELEM (N_VOXELS * COUT)

#define RVOX 64                                  // voxels per range (block)
#define RSHIFT 6
#define NR ((N_VOXELS + RVOX - 1) / RVOX)        // 2344 ranges
#define CAP 1024                                 // bucket cap (avg 691, +12 sigma)

// ws layout (int32 units):
//   [0 .. NR)        range counters
//   [4096 .. 4224)   BN stats (float): sum[64], sumsq[64]
//   [8192 .. )       bucket lists, NR*CAP ints (~9.6 MB)
#define WS_CNT   0
#define WS_STATS 4096
#define WS_LIST  8192

typedef int v16i __attribute__((ext_vector_type(16)));

// ---------------------------------------------------------------------------
// Kernel 1: build range buckets over the flat (k,p) rulebook.
// entry = (k<<24) | (vin<<6) | (vout & 63); vin < 2^18 fits bits 6..23.
// ---------------------------------------------------------------------------
__global__ __launch_bounds__(256) void build_buckets(
    const int* __restrict__ in_idx,
    const int* __restrict__ out_idx,
    int* __restrict__ ws)
{
    const int idx = blockIdx.x * 256 + threadIdx.x;
    if (idx >= NK * NP) return;
    const int k    = idx / NP;
    const int vout = out_idx[idx];
    const int vin  = in_idx[idx];
    const int r    = vout >> RSHIFT;
    const int slot = atomicAdd(&ws[WS_CNT + r], 1);
    if (slot < CAP)
        ws[WS_LIST + r * CAP + slot] = (k << 24) | (vin << RSHIFT) | (vout & (RVOX - 1));
}

// ---------------------------------------------------------------------------
// Kernel 2: gather conv per range, k-binned. Per entry: uniform kbin read ->
// readfirstlane -> feature row fetched through the SCALAR pipe (2x
// s_load_dwordx16 into 32 SGPRs) -> 32 v_fmac (SGPR x VGPR weight column,
// lane = cout) -> one ds_add into the LDS accum tile. No staging, no per-tile
// barriers, no vector-path row traffic.
// Epilogue: y = relu(acc+bias) coalesced store + fused BN stats.
// ---------------------------------------------------------------------------
__global__ __launch_bounds__(256, 6) void conv_gather(
    const float* __restrict__ features,
    const float* __restrict__ weight,
    const float* __restrict__ bias,
    const int* __restrict__ ws_i,
    float* __restrict__ out,
    float* __restrict__ stats)
{
    __shared__ float accum[RVOX * COUT];    // 16 KB
    __shared__ int   kbin[CAP];             // 4 KB
    __shared__ int   khist[NK];
    __shared__ int   koff[NK + 1];
    __shared__ int   kcur[NK];
    __shared__ float lsum[COUT];
    __shared__ float lsq[COUT];

    const int r    = blockIdx.x;
    const int tid  = threadIdx.x;
    const int lane = tid & 63;
    const int wid  = tid >> 6;

    int n = ws_i[WS_CNT + r];
    if (n > CAP) n = CAP;
    const int* list = ws_i + WS_LIST + (size_t)r * CAP;

    float4* acc4 = reinterpret_cast<float4*>(accum);
    for (int i = tid; i < RVOX * COUT / 4; i += 256) acc4[i] = float4{0.f, 0.f, 0.f, 0.f};
    if (tid < NK) khist[tid] = 0;
    if (tid < COUT) { lsum[tid] = 0.f; lsq[tid] = 0.f; }
    __syncthreads();

    // histogram by k, then place into k-sorted bins
    for (int i = tid; i < n; i += 256) atomicAdd(&khist[list[i] >> 24], 1);
    __syncthreads();
    if (tid == 0) {
        int a = 0;
        for (int k = 0; k < NK; ++k) { koff[k] = a; kcur[k] = a; a += khist[k]; }
        koff[NK] = a;
    }
    __syncthreads();
    for (int i = tid; i < n; i += 256) {
        const int pk = list[i];
        kbin[atomicAdd(&kcur[pk >> 24], 1)] = pk;
    }
    __syncthreads();

    for (int k = 0; k < NK; ++k) {
        const int b0 = koff[k], b1 = koff[k + 1];
        if (b0 == b1) continue;

        // weight column for this lane's cout, resident in VGPRs
        float w[CIN];
        const float* wk = weight + k * (CIN * COUT) + lane;
#pragma unroll
        for (int c = 0; c < CIN; ++c) w[c] = wk[c * COUT];

        // each wave takes every-4th entry of this k-segment
        for (int j = b0 + wid; j < b1; j += 4) {
            const int pk  = __builtin_amdgcn_readfirstlane(kbin[j]);   // scalar
            const int vin = (pk >> RSHIFT) & 0x3FFFF;                  // scalar
            const int lv  = pk & (RVOX - 1);                           // scalar
            const float* row = features + (size_t)vin * CIN;           // SGPR pair

            v16i ra, rb;
            asm volatile(
                "s_load_dwordx16 %0, %2, 0\n\t"
                "s_load_dwordx16 %1, %2, 64\n\t"
                "s_waitcnt lgkmcnt(0)"
                : "=&s"(ra), "=&s"(rb)
                : "s"(row));

            float acc = 0.f;
#pragma unroll
            for (int c = 0; c < 16; ++c)
                acc = fmaf(__int_as_float(ra[c]), w[c], acc);
#pragma unroll
            for (int c = 0; c < 16; ++c)
                acc = fmaf(__int_as_float(rb[c]), w[16 + c], acc);

            atomicAdd(&accum[lv * COUT + lane], acc);                  // ds_add_f32
        }
    }
    __syncthreads();

    // epilogue: y = relu(acc + bias), coalesced store, fused BN stats
    const int v0 = r * RVOX;
    const int nv = (N_VOXELS - v0 < RVOX) ? (N_VOXELS - v0) : RVOX;
    const float b = bias[lane];            // channel == tid&63 (stride 256)
    float rs = 0.f, rq = 0.f;
    for (int i = tid; i < nv * COUT; i += 256) {
        float y = accum[i] + b;
        y = fmaxf(y, 0.f);
        out[(size_t)v0 * COUT + i] = y;
        rs += y;
        rq += y * y;
    }
    atomicAdd(&lsum[lane], rs);
    atomicAdd(&lsq[lane], rq);
    __syncthreads();
    if (tid < COUT) atomicAdd(&stats[tid], lsum[tid]);
    else if (tid < 2 * COUT) atomicAdd(&stats[tid], lsq[tid - COUT]);
}

// ---------------------------------------------------------------------------
// Kernel 3: in-place BN apply on y (already ReLU'd), float4-vectorized.
// ---------------------------------------------------------------------------
__global__ __launch_bounds__(256) void bn_apply(
    float* __restrict__ buf,
    const float* __restrict__ stats,
    const float* __restrict__ gamma,
    const float* __restrict__ beta)
{
    const float inv_n = 1.f / (float)N_VOXELS;
    const int cg = (threadIdx.x & 15) * 4;
    float sc[4], sh[4];
#pragma unroll
    for (int j = 0; j < 4; ++j) {
        const int c = cg + j;
        const float mean = stats[c] * inv_n;
        const float var  = stats[COUT + c] * inv_n - mean * mean;
        sc[j] = gamma[c] * rsqrtf(var + BN_EPS);
        sh[j] = beta[c] - mean * sc[j];
    }
    const int tid    = blockIdx.x * 256 + threadIdx.x;
    const int stride = gridDim.x * 256;
    float4* buf4 = reinterpret_cast<float4*>(buf);
    for (int i = tid; i < NELEM / 4; i += stride) {
        float4 y = buf4[i];
        y.x = fmaf(y.x, sc[0], sh[0]);
        y.y = fmaf(y.y, sc[1], sh[1]);
        y.z = fmaf(y.z, sc[2], sh[2]);
        y.w = fmaf(y.w, sc[3], sh[3]);
        buf4[i] = y;
    }
}

extern "C" void kernel_launch(void* const* d_in, const int* in_sizes, int n_in,
                              void* d_out, int out_size, void* d_ws, size_t ws_size,
                              hipStream_t stream) {
    const float* features = (const float*)d_in[0];
    const int*   in_idx   = (const int*)d_in[1];
    const int*   out_idx  = (const int*)d_in[2];
    const float* weight   = (const float*)d_in[3];
    const float* bias     = (const float*)d_in[4];
    const float* gamma    = (const float*)d_in[5];
    const float* beta     = (const float*)d_in[6];
    float* out   = (float*)d_out;
    int*   ws    = (int*)d_ws;
    float* stats = (float*)d_ws + WS_STATS;

    // zero counters + stats (first 32 KB); bucket payload needs no init
    hipMemsetAsync(d_ws, 0, (size_t)WS_LIST * sizeof(int), stream);

    build_buckets<<<(NK * NP + 255) / 256, 256, 0, stream>>>(in_idx, out_idx, ws);

    conv_gather<<<NR, 256, 0, stream>>>(features, weight, bias, ws, out, stats);

    bn_apply<<<2048, 256, 0, stream>>>(out, stats, gamma, beta);
}